// Round 1
// baseline (107.470 us; speedup 1.0000x reference)
//
#include <hip/hip_runtime.h>
#include <math.h>

#define PH 7
#define PW 7
#define BB 4
#define HH 64
#define WW 64
#define CC 256
#define RR 128
#define NBINS (BB * RR * PH * PW)   // 25088, divisible by 4

// One wave (64 lanes) per output bin; lane l handles channels 4l..4l+3 as a
// float4. Every global load is 64 lanes x 16B = 1KB contiguous (one pixel's
// 256 channels). Block = 256 threads = 4 waves = 4 bins.
__global__ __launch_bounds__(256) void ROIPoolingLayer_62079457296467_kernel(
    const float* __restrict__ fm, const float* __restrict__ rois,
    float* __restrict__ out)
{
    const int wave = threadIdx.x >> 6;
    const int lane = threadIdx.x & 63;
    const int gbin = blockIdx.x * 4 + wave;          // global bin id, < NBINS

    const int br  = gbin / (PH * PW);                // (b,r) flat index
    const int bin = gbin - br * (PH * PW);           // 0..48
    const int b   = br >> 7;                         // / RR (=128)
    const int ph  = bin / PW;
    const int pw  = bin - ph * PW;

    // ROI decode — replicate reference fp32 math exactly.
    const float4 roi = ((const float4*)rois)[br];
    const int h0 = (int)floorf((float)HH * roi.x);
    const int w0 = (int)floorf((float)WW * roi.y);
    const int h1 = (int)floorf((float)HH * roi.z);
    const int w1 = (int)floorf((float)WW * roi.w);
    const int rh = h1 - h0;
    const int rw = w1 - w0;
    const int hstep = max(rh / PH, 1);
    const int wstep = max(rw / PW, 1);

    // Bin pixel ranges. For ph < PH-1 the range is [ph*hstep, (ph+1)*hstep);
    // the last bin extends to the region end. Clamp by region (covers the
    // degenerate rh < PH case -> empty bin -> -inf, matching segment_max).
    int hs = h0 + ph * hstep;
    int he = (ph == PH - 1) ? (h0 + rh) : (hs + hstep);
    he = min(he, h0 + rh);  he = min(he, HH);
    int ws = w0 + pw * wstep;
    int we = (pw == PW - 1) ? (w0 + rw) : (ws + wstep);
    we = min(we, w0 + rw);  we = min(we, WW);

    const float4* __restrict__ fm4 =
        (const float4*)fm + (size_t)b * (HH * WW) * (CC / 4) + lane;

    float4 acc = make_float4(-INFINITY, -INFINITY, -INFINITY, -INFINITY);
    for (int h = hs; h < he; ++h) {
        const float4* rowp = fm4 + (size_t)h * WW * (CC / 4);
        for (int w = ws; w < we; ++w) {
            float4 v = rowp[(size_t)w * (CC / 4)];
            acc.x = fmaxf(acc.x, v.x);
            acc.y = fmaxf(acc.y, v.y);
            acc.z = fmaxf(acc.z, v.z);
            acc.w = fmaxf(acc.w, v.w);
        }
    }

    ((float4*)out)[(size_t)gbin * (CC / 4) + lane] = acc;
}

extern "C" void kernel_launch(void* const* d_in, const int* in_sizes, int n_in,
                              void* d_out, int out_size, void* d_ws, size_t ws_size,
                              hipStream_t stream) {
    const float* fm   = (const float*)d_in[0];
    const float* rois = (const float*)d_in[1];
    float* out        = (float*)d_out;
    ROIPoolingLayer_62079457296467_kernel<<<NBINS / 4, 256, 0, stream>>>(fm, rois, out);
}

// Round 2
// 106.886 us; speedup vs baseline: 1.0055x; 1.0055x over previous
//
#include <hip/hip_runtime.h>
#include <math.h>

#define PH 7
#define PW 7
#define BB 4
#define HH 64
#define WW 64
#define CC 256
#define RR 128
#define CH4 (CC / 4)                 // 64 float4 per pixel
#define NROWS (BB * RR * PH)         // 3584 waves, one per (b,r,ph)
#define NBLK (NROWS / 4)             // 896 blocks of 4 waves

typedef float f4 __attribute__((ext_vector_type(4)));

__device__ __forceinline__ f4 max4(f4 a, f4 b) {
    f4 r;
    r.x = fmaxf(a.x, b.x); r.y = fmaxf(a.y, b.y);
    r.z = fmaxf(a.z, b.z); r.w = fmaxf(a.w, b.w);
    return r;
}

// One wave per (b, r, ph): computes all 7 pw bins of that pooled row.
// Lane l = channels 4l..4l+3 (float4) -> every load is a 1KB coalesced
// wave transaction. 7 independent loads per inner iteration (one per bin)
// for MLP. XCD swizzle: blocks dispatch round-robin over 8 XCDs; map so
// image b's ROIs land on XCDs {2b, 2b+1} (fm slice 4.2MB ~ one L2).
__global__ __launch_bounds__(256) void ROIPoolingLayer_62079457296467_kernel(
    const float* __restrict__ fm, const float* __restrict__ rois,
    float* __restrict__ out)
{
    const int wave = threadIdx.x >> 6;
    const int lane = threadIdx.x & 63;

    // ---- XCD-aware swizzle: 896 blocks = 8 xcd * 112 slots ----
    const int bid  = blockIdx.x;
    const int xcd  = bid & 7;
    const int slot = bid >> 3;                    // 0..111
    const int b    = xcd >> 1;                    // image 0..3
    const int idx  = (xcd & 1) * 112 + slot;      // 0..223 within image
    const int ri   = idx * 4 + wave;              // 0..895 = (r,ph) flat
    const int r    = ri / 7;
    const int ph   = ri - r * 7;
    const int br   = b * RR + r;

    // ---- ROI decode (reference fp32 semantics, truncating casts) ----
    const f4 roi = ((const f4*)rois)[br];
    const int h0 = (int)floorf((float)HH * roi.x);
    const int w0 = (int)floorf((float)WW * roi.y);
    const int h1 = (int)floorf((float)HH * roi.z);
    const int w1 = (int)floorf((float)WW * roi.w);
    const int rh = h1 - h0;
    const int rw = w1 - w0;
    const int hstep = max(rh / PH, 1);
    const int wstep = max(rw / PW, 1);

    // Row range for this ph bin (last bin extends to region end).
    int hs = h0 + ph * hstep;
    int he = (ph == PH - 1) ? (h0 + rh) : (hs + hstep);
    he = min(he, h0 + rh);

    const f4* __restrict__ fmb =
        (const f4*)fm + (size_t)b * (HH * WW) * CH4 + lane;

    f4 acc[PW];
#pragma unroll
    for (int k = 0; k < PW; ++k)
        acc[k] = (f4){-INFINITY, -INFINITY, -INFINITY, -INFINITY};

    for (int h = hs; h < he; ++h) {
        const f4* rowp = fmb + (size_t)h * (WW * CH4);
        // Bins 0..6 all cover w = w0 + k*wstep + j for j in [0,wstep)
        // (valid for k==6 too since rw >= 7*wstep). 7 independent loads.
        for (int j = 0; j < wstep; ++j) {
            f4 v[PW];
#pragma unroll
            for (int k = 0; k < PW; ++k)
                v[k] = rowp[(size_t)(w0 + k * wstep + j) * CH4];
#pragma unroll
            for (int k = 0; k < PW; ++k)
                acc[k] = max4(acc[k], v[k]);
        }
        // Bin 6 tail: w in [w0+7*wstep, w0+rw)  (0..6 pixels)
        for (int w = w0 + PW * wstep; w < w0 + rw; ++w)
            acc[PW - 1] = max4(acc[PW - 1], rowp[(size_t)w * CH4]);
    }

    // Output (b,r,ph,pw,C): 7 contiguous float4 stores per lane.
    // Non-temporal: out is never re-read; keep fm resident in L2.
    f4* outp = (f4*)out + ((size_t)br * PH + ph) * PW * CH4 + lane;
#pragma unroll
    for (int k = 0; k < PW; ++k)
        __builtin_nontemporal_store(acc[k], outp + (size_t)k * CH4);
}

extern "C" void kernel_launch(void* const* d_in, const int* in_sizes, int n_in,
                              void* d_out, int out_size, void* d_ws, size_t ws_size,
                              hipStream_t stream) {
    const float* fm   = (const float*)d_in[0];
    const float* rois = (const float*)d_in[1];
    float* out        = (float*)d_out;
    ROIPoolingLayer_62079457296467_kernel<<<NBLK, 256, 0, stream>>>(fm, rois, out);
}

// Round 3
// 89.367 us; speedup vs baseline: 1.2026x; 1.1960x over previous
//
#include <hip/hip_runtime.h>
#include <math.h>

#define PH 7
#define PW 7
#define BB 4
#define HH 64
#define WW 64
#define CC 256
#define RR 128
#define CH4 (CC / 4)                   // 64 float4 per pixel
#define BINS_PER_IMG (RR * PH * PW)    // 6272
#define NBINS (BB * BINS_PER_IMG)      // 25088
#define NBLK (NBINS / 4)               // 6272 blocks, 4 waves each
#define BLK_PER_IMG (NBLK / 8)         // 784 per xcd slot

typedef float f4 __attribute__((ext_vector_type(4)));

__device__ __forceinline__ f4 max4(f4 a, f4 b) {
    f4 r;
    r.x = fmaxf(a.x, b.x); r.y = fmaxf(a.y, b.y);
    r.z = fmaxf(a.z, b.z); r.w = fmaxf(a.w, b.w);
    return r;
}

// One wave per output bin (TLP: 25088 waves) + 8 pixel-loads in flight per
// round (MLP). Lane l = channels 4l..4l+3 -> each load is a 1KB coalesced
// wave transaction; all bin/pixel index math is wave-uniform (scalar pipe).
// Flattened pixel index p -> (h,w) via 16-bit magic divide by wbin (exact:
// p<=~81, err term p*e < 2^16). OOB p clamps to npix-1; duplicate loads are
// idempotent under max. XCD swizzle keeps each image's fm slice (4.2MB) hot
// in one XCD-pair's L2 (R2 evidence: FETCH 50->12MB).
__global__ __launch_bounds__(256) void ROIPoolingLayer_62079457296467_kernel(
    const float* __restrict__ fm, const float* __restrict__ rois,
    float* __restrict__ out)
{
    const int wave = threadIdx.x >> 6;
    const int lane = threadIdx.x & 63;

    // ---- XCD swizzle: 6272 blocks = 8 xcds x 784; image b -> xcds {2b,2b+1}
    const int bid   = blockIdx.x;
    const int xcd   = bid & 7;
    const int slot  = bid >> 3;                     // 0..783
    const int b     = xcd >> 1;                     // image 0..3
    const int blkin = (xcd & 1) * BLK_PER_IMG + slot;  // 0..1567 in image
    const int local = blkin * 4 + wave;             // 0..6271 = r*49 + bin
    const int r     = local / (PH * PW);
    const int bin   = local - r * (PH * PW);
    const int ph    = bin / PW;
    const int pw    = bin - ph * PW;
    const int br    = b * RR + r;

    // ---- ROI decode (reference fp32 semantics, truncating casts) ----
    const f4 roi = ((const f4*)rois)[br];
    const int h0 = (int)floorf((float)HH * roi.x);
    const int w0 = (int)floorf((float)WW * roi.y);
    const int h1 = (int)floorf((float)HH * roi.z);
    const int w1 = (int)floorf((float)WW * roi.w);
    const int rh = h1 - h0;
    const int rw = w1 - w0;
    const int hstep = max(rh / PH, 1);
    const int wstep = max(rw / PW, 1);

    // Bin window [hs,he) x [ws,we); last bin extends to region end.
    int hs = h0 + ph * hstep;
    int he = (ph == PH - 1) ? (h0 + rh) : (hs + hstep);
    he = min(he, h0 + rh);  he = min(he, HH);
    int ws = w0 + pw * wstep;
    int we = (pw == PW - 1) ? (w0 + rw) : (ws + wstep);
    we = min(we, w0 + rw);  we = min(we, WW);

    const int hbin = he - hs;
    const int wbin = we - ws;
    const int npix = hbin * wbin;

    const f4* __restrict__ fmb =
        (const f4*)fm + ((size_t)b * HH + hs) * (WW * CH4) + (size_t)ws * CH4 + lane;

    f4 acc = (f4){-INFINITY, -INFINITY, -INFINITY, -INFINITY};

    if (npix > 0) {
        // magic divide by wbin: q = (p*m)>>16 == p/wbin for p*e < 2^16
        const unsigned m = (65536u + (unsigned)wbin - 1) / (unsigned)wbin;
        for (int p = 0; p < npix; p += 8) {
            f4 v[8];
#pragma unroll
            for (int k = 0; k < 8; ++k) {
                const int pk = min(p + k, npix - 1);        // clamp: dup ok
                const int q  = (int)(((unsigned)pk * m) >> 16);  // row in bin
                const int w  = pk - q * wbin;                    // col in bin
                v[k] = fmb[((size_t)q * WW + w) * CH4];
            }
#pragma unroll
            for (int k = 0; k < 8; ++k)
                acc = max4(acc, v[k]);
        }
    }

    // Output (b,r,ph,pw,C): gbin = b*6272 + local; non-temporal (never re-read).
    const size_t gbin = (size_t)b * BINS_PER_IMG + local;
    __builtin_nontemporal_store(acc, (f4*)out + gbin * CH4 + lane);
}

extern "C" void kernel_launch(void* const* d_in, const int* in_sizes, int n_in,
                              void* d_out, int out_size, void* d_ws, size_t ws_size,
                              hipStream_t stream) {
    const float* fm   = (const float*)d_in[0];
    const float* rois = (const float*)d_in[1];
    float* out        = (float*)d_out;
    ROIPoolingLayer_62079457296467_kernel<<<NBLK, 256, 0, stream>>>(fm, rois, out);
}